// Round 9
// baseline (151.497 us; speedup 1.0000x reference)
//
#include <hip/hip_runtime.h>

#define HH 512
#define WW 512
#define NCH 3
#define NBATCH 16
#define NIMG (NBATCH*NCH)     // 48
#define CHUNK 16              // output rows per wave (R16: was 32 — grid x2)
#define NCHUNK (HH/CHUNK)     // 32
#define NSTRIP 4              // 128-col strips
#define SW 128
#define SLOTS 142             // pad=6: col c <-> slot c-c0+6, slots 0..141
#define NT 64                 // one wave per block -> no barriers anywhere
#define BLKS_PER_B (NCH*NCHUNK*NSTRIP)   // 384 partial slots per batch elem

struct RowData { float4 m; float2 h; };

// R16 = R15 (ring-free vertical slide, passed, absmax 0.0) + two fixes:
//  (a) WARMUP DEAD WORK CUT: bodies 0..9 only need the vertical slide; the
//      staging + 14 tap reads + horizontal sums they did were discarded
//      (leftover shape from the ring structure). Now slide-only.
//  (b) GRID x2 (CHUNK 32->16): R15 showed occupancy capped by the GRID
//      (12 blocks/CU; LDS 2560B would allow ~25, VGPR 64 allows 32 waves).
//      All pipes unsaturated (VALU 37%, LDS ~60%, HBM 35%) -> latency-bound,
//      needs more waves. 6144 blocks = 24/CU. Cost: +24% input rows
//      (26 per 16 outputs vs 42 per 32), mostly L3-absorbed.
//  Structure rationale unchanged (R7-R15): fp16 ring killed occupancy;
//  register-ring died 3x to scratch; so vertical sums live in registers and
//  the row leaving the window is re-loaded from global + products recomputed.
__global__ __launch_bounds__(NT) void ssim_main(
    const float* __restrict__ pred, const float* __restrict__ targ,
    float* __restrict__ ws)
{
  // vertical-sum staging: slot s holds col c0+s-6 (same-wave in-order LDS;
  // no barriers — validated R2-R15)
  __shared__ __align__(16) float2 arrA[SLOTS];   // (Sx, Sy) per col
  __shared__ __align__(16) float2 arrB[SLOTS];   // (Sxy, Sss) per col

  const int l = threadIdx.x;
  const int blk = blockIdx.x;
  const int img = blk >> 7;              // / (NCHUNK*NSTRIP) = /128
  const int rem = blk & 127;
  const int chunk = rem >> 2;
  const int strip = rem & 3;

  const int r0 = chunk*CHUNK - 5;        // first input row
  const int c0 = strip*SW;

  const size_t ib = (size_t)img * (size_t)(HH*WW);
  const float* pp = pred + ib;
  const float* tp = targ + ib;

  const int cm = c0 + 2*l;               // this lane's 2 main cols
  const int h  = l - 54;                 // halo id 0..9 on lanes 54..63
  const int ch = (h < 5) ? (c0 - 5 + h) : (c0 + 123 + h);   // halo col
  const bool hval = (l >= 54) && ((unsigned)ch < (unsigned)WW);
  const int hs = (h < 5) ? (1 + h) : (129 + h);  // halo slot (pad=6)

  auto loadrow = [&](int it) -> RowData {
    RowData d;
    const int r = r0 + it;
    if ((unsigned)r < (unsigned)HH) {    // wave-uniform branch
      const size_t ro = (size_t)r * WW;
      const float2 x = *(const float2*)(pp + ro + cm);
      const float2 y = *(const float2*)(tp + ro + cm);
      d.m = make_float4(x.x, x.y, y.x, y.y);
      if (hval) d.h = make_float2(pp[ro + ch], tp[ro + ch]);
      else      d.h = make_float2(0.f, 0.f);
    } else {
      d.m = make_float4(0.f, 0.f, 0.f, 0.f);
      d.h = make_float2(0.f, 0.f);
    }
    return d;
  };

  // old-row stream: zero when the ITERATION index is pre-window (it<0),
  // independent of image bounds (which loadrow already zero-pads).
  // R14 lesson: the pre-window is EMPTY — never subtract real rows in warmup.
  auto loadold = [&](int it) -> RowData {
    if (it >= 0) return loadrow(it);     // wave-uniform branch
    RowData d;
    d.m = make_float4(0.f, 0.f, 0.f, 0.f);
    d.h = make_float2(0.f, 0.f);
    return d;
  };

  // vertical running sums over the 11-row window — all registers, no history
  float vx0=0.f, vy0=0.f, vxy0=0.f, vss0=0.f;    // main col 0 (cm)
  float vx1=0.f, vy1=0.f, vxy1=0.f, vss1=0.f;    // main col 1 (cm+1)
  float vxh=0.f, vyh=0.f, vxyh=0.f, vssh=0.f;    // halo col (lanes 54..63)
  float acc = 0.f;

  // prefetch: new-row stream 3-deep (HBM), old-row stream 1-deep (L2/L3 hit)
  RowData curN = loadrow(0);
  RowData nxtN = loadrow(1);
  RowData nx2N = loadrow(2);
  RowData curO = loadold(-11);           // pre-window -> zeros

  constexpr float c1 = 0.0001f, c2 = 0.0009f, inv121 = 1.0f/121.0f;

  auto ssim1 = [&](float Sx, float Sy, float Sxy, float Sss) -> float {
    const float mux = Sx*inv121, muy = Sy*inv121;
    const float muxy = mux*muy;
    const float m2   = fmaf(mux, mux, muy*muy);
    const float sgxy = fmaf(Sxy, inv121, -muxy);
    const float sgss = fmaf(Sss, inv121, -m2);
    const float num = fmaf(2.f, muxy, c1) * fmaf(2.f, sgxy, c2);
    const float den = (m2 + c1) * (sgss + c2);
    const float s = num * __builtin_amdgcn_rcpf(den);
    return fminf(fmaxf(s, 0.f), 1.f);
  };

  auto body = [&](int it, bool doemit) {
    // 1) vertical window slide: add new row, subtract old row (zero if
    //    pre-window or out of image). Products recomputed identically on add
    //    and subtract -> drift is ~ulp-level only.
    {
      const float xn0 = curN.m.x, xn1 = curN.m.y;
      const float yn0 = curN.m.z, yn1 = curN.m.w;
      const float xo0 = curO.m.x, xo1 = curO.m.y;
      const float yo0 = curO.m.z, yo1 = curO.m.w;
      vx0  += xn0 - xo0;  vy0  += yn0 - yo0;
      vx1  += xn1 - xo1;  vy1  += yn1 - yo1;
      vxy0 += xn0*yn0 - xo0*yo0;
      vxy1 += xn1*yn1 - xo1*yo1;
      vss0 += fmaf(xn0, xn0, yn0*yn0) - fmaf(xo0, xo0, yo0*yo0);
      vss1 += fmaf(xn1, xn1, yn1*yn1) - fmaf(xo1, xo1, yo1*yo1);
      const float xnh = curN.h.x, ynh = curN.h.y;
      const float xoh = curO.h.x, yoh = curO.h.y;
      vxh  += xnh - xoh;  vyh  += ynh - yoh;
      vxyh += xnh*ynh - xoh*yoh;
      vssh += fmaf(xnh, xnh, ynh*ynh) - fmaf(xoh, xoh, yoh*yoh);
    }

    // 2) advance prefetch streams (old row issued a full body before use)
    curN = nxtN; nxtN = nx2N;
    nx2N = loadrow(it + 3);
    RowData oN = loadold(it - 10);       // old row for body it+1

    if (doemit) {
      // 3) stage vertical sums: ONE aligned conflict-free b128 per array
      //    (byte 48+16l, 16B/lane stride) + halo b64 on 10 lanes
      *(float4*)(arrA + 6 + 2*l) = make_float4(vx0, vy0, vx1, vy1);
      *(float4*)(arrB + 6 + 2*l) = make_float4(vxy0, vss0, vxy1, vss1);
      if (l >= 54) {
        arrA[hs] = make_float2(vxh, vyh);
        arrB[hs] = make_float2(vxyh, vssh);
      }

      // 4) horizontal 11-tap window, pure adds. Element j of the b128 read
      //    at (float4*)arrA + l + j covers slots {2l+2j, 2l+2j+1}; col0
      //    window = slots 2l+1..2l+11, col1 = col0 - slot(2l+1) + slot(2l+12)
      const float4* ta = (const float4*)(arrA) + l;
      const float4 a0v = ta[0], a1v = ta[1], a2v = ta[2], a3v = ta[3],
                   a4v = ta[4], a5v = ta[5], a6v = ta[6];
      const float4* tb = (const float4*)(arrB) + l;
      const float4 b0v = tb[0], b1v = tb[1], b2v = tb[2], b3v = tb[3],
                   b4v = tb[4], b5v = tb[5], b6v = tb[6];

      float Sx = a0v.z, Sy = a0v.w;
      Sx += a1v.x; Sy += a1v.y;  Sx += a1v.z; Sy += a1v.w;
      Sx += a2v.x; Sy += a2v.y;  Sx += a2v.z; Sy += a2v.w;
      Sx += a3v.x; Sy += a3v.y;  Sx += a3v.z; Sy += a3v.w;
      Sx += a4v.x; Sy += a4v.y;  Sx += a4v.z; Sy += a4v.w;
      Sx += a5v.x; Sy += a5v.y;  Sx += a5v.z; Sy += a5v.w;
      const float Sx1 = Sx - a0v.z + a6v.x;
      const float Sy1 = Sy - a0v.w + a6v.y;

      float Sxy = b0v.z, Sss = b0v.w;
      Sxy += b1v.x; Sss += b1v.y;  Sxy += b1v.z; Sss += b1v.w;
      Sxy += b2v.x; Sss += b2v.y;  Sxy += b2v.z; Sss += b2v.w;
      Sxy += b3v.x; Sss += b3v.y;  Sxy += b3v.z; Sss += b3v.w;
      Sxy += b4v.x; Sss += b4v.y;  Sxy += b4v.z; Sss += b4v.w;
      Sxy += b5v.x; Sss += b5v.y;  Sxy += b5v.z; Sss += b5v.w;
      const float Sxy1 = Sxy - b0v.z + b6v.x;
      const float Sss1 = Sss - b0v.w + b6v.y;

      acc += ssim1(Sx,  Sy,  Sxy,  Sss);
      acc += ssim1(Sx1, Sy1, Sxy1, Sss1);
    }
    curO = oN;
  };

  // 26 input rows: warmup 10 (slide-only), then 16 emitting bodies.
  // Moderate unroll with REAL back-edges (R11: straight-line bodies ->
  // giant live ranges -> 256 VGPR + 300MB scratch; never again).
  #pragma clang loop unroll_count(2)
  for (int it = 0; it < 10; ++it) body(it, false);
  #pragma clang loop unroll_count(2)
  for (int it = 10; it < 26; ++it) body(it, true);

  // wave reduction -> per-block partial slot (written unconditionally: no
  // memset of d_ws needed, no atomics)
  #pragma unroll
  for (int off = 32; off > 0; off >>= 1) acc += __shfl_down(acc, off, 64);
  if (l == 0) ws[blk] = acc;
}

__global__ void ssim_final(const float* __restrict__ ws, float* __restrict__ out) {
  const int b = blockIdx.x;              // batch element
  const int t = threadIdx.x;             // 64 threads
  const float* p = ws + b * BLKS_PER_B;  // 384 partials per batch elem
  float s = 0.f;
  #pragma unroll
  for (int k = 0; k < BLKS_PER_B/64; ++k) s += p[t + 64*k];
  #pragma unroll
  for (int off = 32; off > 0; off >>= 1) s += __shfl_down(s, off, 64);
  if (t == 0) out[b] = 1.0f - s * (1.0f / (float)(NCH*HH*WW));
}

extern "C" void kernel_launch(void* const* d_in, const int* in_sizes, int n_in,
                              void* d_out, int out_size, void* d_ws, size_t ws_size,
                              hipStream_t stream) {
  const float* pred = (const float*)d_in[0];
  const float* targ = (const float*)d_in[1];
  float* out = (float*)d_out;
  float* ws  = (float*)d_ws;
  ssim_main<<<dim3(NIMG*NCHUNK*NSTRIP), dim3(NT), 0, stream>>>(pred, targ, ws);
  ssim_final<<<dim3(NBATCH), dim3(64), 0, stream>>>(ws, out);
}

// Round 10
// 147.438 us; speedup vs baseline: 1.0275x; 1.0275x over previous
//
#include <hip/hip_runtime.h>

#define HH 512
#define WW 512
#define NCH 3
#define NBATCH 16
#define NIMG (NBATCH*NCH)     // 48
#define CHUNK 16              // output rows per wave
#define NCHUNK (HH/CHUNK)     // 32
#define NSTRIP 4              // 128-col strips
#define SW 128
#define SLOTS 142             // pad=6: col c <-> slot c-c0+6, slots 0..141
#define NWAVE 4               // waves per block (independent units, no barriers)
#define NT (64*NWAVE)         // 256 threads
#define NUNITS (NIMG*NCHUNK*NSTRIP)      // 6144 wave-units
#define BLKS_PER_B (NCH*NCHUNK*NSTRIP)   // 384 partial slots per batch elem

struct RowData { float4 m; float2 h; };

// R17 = R16 algorithm, 4 INDEPENDENT WAVES PER WORKGROUP.
//  R16 post-mortem: grid x2 (24 blocks/CU wanted) moved occupancy only
//  28->31% — single-wave workgroups hit the ~16 wg/CU hardware cap, so
//  occupancy can never exceed ~16 waves/CU regardless of grid. Fix: pack 4
//  independent wave-units into one 256-thread block, each with its own LDS
//  slice (arrA[wid]); no inter-wave data sharing -> still ZERO barriers.
//  6 blocks/CU x 4 waves = 24 waves/CU (LDS 9088B x7 fits 64KB pool; VGPR 64
//  allows 8 waves/SIMD). Unit id = blockIdx.x*4+wid keeps the exact ws
//  layout -> ssim_final unchanged.
//  Per-wave algorithm (R15/R16, absmax 0.0): vertical running sums in
//  registers; row leaving the window re-loaded from global (11-row reuse ->
//  L2/L3 hit) with products recomputed; per emit-body stage 4 sums/col into
//  two float2 LDS arrays (ONE conflict-free b128 write each) and do the
//  horizontal 11-tap window as pure adds (7 conflict-free b128 reads each);
//  warmup bodies are slide-only (no staging, no taps).
__global__ __launch_bounds__(NT) void ssim_main(
    const float* __restrict__ pred, const float* __restrict__ targ,
    float* __restrict__ ws)
{
  // per-wave vertical-sum staging slices (same-wave in-order LDS; no barriers
  // — validated R2-R16). Row stride 142*8B = 16B multiple -> rows 16B-aligned.
  __shared__ __align__(16) float2 arrA[NWAVE][SLOTS];   // (Sx, Sy) per col
  __shared__ __align__(16) float2 arrB[NWAVE][SLOTS];   // (Sxy, Sss) per col

  const int tid = threadIdx.x;
  const int wid = tid >> 6;              // wave id 0..3
  const int l   = tid & 63;              // lane id
  const int unit = blockIdx.x * NWAVE + wid;   // == old single-wave blk id
  const int img = unit >> 7;             // / (NCHUNK*NSTRIP) = /128
  const int rem = unit & 127;
  const int chunk = rem >> 2;
  const int strip = rem & 3;

  const int r0 = chunk*CHUNK - 5;        // first input row
  const int c0 = strip*SW;

  const size_t ib = (size_t)img * (size_t)(HH*WW);
  const float* pp = pred + ib;
  const float* tp = targ + ib;

  const int cm = c0 + 2*l;               // this lane's 2 main cols
  const int h  = l - 54;                 // halo id 0..9 on lanes 54..63
  const int ch = (h < 5) ? (c0 - 5 + h) : (c0 + 123 + h);   // halo col
  const bool hval = (l >= 54) && ((unsigned)ch < (unsigned)WW);
  const int hs = (h < 5) ? (1 + h) : (129 + h);  // halo slot (pad=6)

  float2* const wA = arrA[wid];
  float2* const wB = arrB[wid];

  auto loadrow = [&](int it) -> RowData {
    RowData d;
    const int r = r0 + it;
    if ((unsigned)r < (unsigned)HH) {    // wave-uniform branch
      const size_t ro = (size_t)r * WW;
      const float2 x = *(const float2*)(pp + ro + cm);
      const float2 y = *(const float2*)(tp + ro + cm);
      d.m = make_float4(x.x, x.y, y.x, y.y);
      if (hval) d.h = make_float2(pp[ro + ch], tp[ro + ch]);
      else      d.h = make_float2(0.f, 0.f);
    } else {
      d.m = make_float4(0.f, 0.f, 0.f, 0.f);
      d.h = make_float2(0.f, 0.f);
    }
    return d;
  };

  // old-row stream: zero when the ITERATION index is pre-window (it<0),
  // independent of image bounds (R14 lesson: pre-window is EMPTY).
  auto loadold = [&](int it) -> RowData {
    if (it >= 0) return loadrow(it);     // wave-uniform branch
    RowData d;
    d.m = make_float4(0.f, 0.f, 0.f, 0.f);
    d.h = make_float2(0.f, 0.f);
    return d;
  };

  // vertical running sums over the 11-row window — all registers, no history
  float vx0=0.f, vy0=0.f, vxy0=0.f, vss0=0.f;    // main col 0 (cm)
  float vx1=0.f, vy1=0.f, vxy1=0.f, vss1=0.f;    // main col 1 (cm+1)
  float vxh=0.f, vyh=0.f, vxyh=0.f, vssh=0.f;    // halo col (lanes 54..63)
  float acc = 0.f;

  // prefetch: new-row stream 3-deep (HBM), old-row stream 1-deep (L2/L3 hit)
  RowData curN = loadrow(0);
  RowData nxtN = loadrow(1);
  RowData nx2N = loadrow(2);
  RowData curO = loadold(-11);           // pre-window -> zeros

  constexpr float c1 = 0.0001f, c2 = 0.0009f, inv121 = 1.0f/121.0f;

  auto ssim1 = [&](float Sx, float Sy, float Sxy, float Sss) -> float {
    const float mux = Sx*inv121, muy = Sy*inv121;
    const float muxy = mux*muy;
    const float m2   = fmaf(mux, mux, muy*muy);
    const float sgxy = fmaf(Sxy, inv121, -muxy);
    const float sgss = fmaf(Sss, inv121, -m2);
    const float num = fmaf(2.f, muxy, c1) * fmaf(2.f, sgxy, c2);
    const float den = (m2 + c1) * (sgss + c2);
    const float s = num * __builtin_amdgcn_rcpf(den);
    return fminf(fmaxf(s, 0.f), 1.f);
  };

  auto body = [&](int it, bool doemit) {
    // 1) vertical window slide: add new row, subtract old row (zero if
    //    pre-window or out of image). Products recomputed identically on add
    //    and subtract -> drift is ~ulp-level only.
    {
      const float xn0 = curN.m.x, xn1 = curN.m.y;
      const float yn0 = curN.m.z, yn1 = curN.m.w;
      const float xo0 = curO.m.x, xo1 = curO.m.y;
      const float yo0 = curO.m.z, yo1 = curO.m.w;
      vx0  += xn0 - xo0;  vy0  += yn0 - yo0;
      vx1  += xn1 - xo1;  vy1  += yn1 - yo1;
      vxy0 += xn0*yn0 - xo0*yo0;
      vxy1 += xn1*yn1 - xo1*yo1;
      vss0 += fmaf(xn0, xn0, yn0*yn0) - fmaf(xo0, xo0, yo0*yo0);
      vss1 += fmaf(xn1, xn1, yn1*yn1) - fmaf(xo1, xo1, yo1*yo1);
      const float xnh = curN.h.x, ynh = curN.h.y;
      const float xoh = curO.h.x, yoh = curO.h.y;
      vxh  += xnh - xoh;  vyh  += ynh - yoh;
      vxyh += xnh*ynh - xoh*yoh;
      vssh += fmaf(xnh, xnh, ynh*ynh) - fmaf(xoh, xoh, yoh*yoh);
    }

    // 2) advance prefetch streams (old row issued a full body before use)
    curN = nxtN; nxtN = nx2N;
    nx2N = loadrow(it + 3);
    RowData oN = loadold(it - 10);       // old row for body it+1

    if (doemit) {
      // 3) stage vertical sums: ONE aligned conflict-free b128 per array
      //    (16B/lane stride) + halo b64 on 10 lanes
      *(float4*)(wA + 6 + 2*l) = make_float4(vx0, vy0, vx1, vy1);
      *(float4*)(wB + 6 + 2*l) = make_float4(vxy0, vss0, vxy1, vss1);
      if (l >= 54) {
        wA[hs] = make_float2(vxh, vyh);
        wB[hs] = make_float2(vxyh, vssh);
      }

      // 4) horizontal 11-tap window, pure adds. Element j of the b128 read
      //    at (float4*)wA + l + j covers slots {2l+2j, 2l+2j+1}; col0
      //    window = slots 2l+1..2l+11, col1 = col0 - slot(2l+1) + slot(2l+12)
      const float4* ta = (const float4*)(wA) + l;
      const float4 a0v = ta[0], a1v = ta[1], a2v = ta[2], a3v = ta[3],
                   a4v = ta[4], a5v = ta[5], a6v = ta[6];
      const float4* tb = (const float4*)(wB) + l;
      const float4 b0v = tb[0], b1v = tb[1], b2v = tb[2], b3v = tb[3],
                   b4v = tb[4], b5v = tb[5], b6v = tb[6];

      float Sx = a0v.z, Sy = a0v.w;
      Sx += a1v.x; Sy += a1v.y;  Sx += a1v.z; Sy += a1v.w;
      Sx += a2v.x; Sy += a2v.y;  Sx += a2v.z; Sy += a2v.w;
      Sx += a3v.x; Sy += a3v.y;  Sx += a3v.z; Sy += a3v.w;
      Sx += a4v.x; Sy += a4v.y;  Sx += a4v.z; Sy += a4v.w;
      Sx += a5v.x; Sy += a5v.y;  Sx += a5v.z; Sy += a5v.w;
      const float Sx1 = Sx - a0v.z + a6v.x;
      const float Sy1 = Sy - a0v.w + a6v.y;

      float Sxy = b0v.z, Sss = b0v.w;
      Sxy += b1v.x; Sss += b1v.y;  Sxy += b1v.z; Sss += b1v.w;
      Sxy += b2v.x; Sss += b2v.y;  Sxy += b2v.z; Sss += b2v.w;
      Sxy += b3v.x; Sss += b3v.y;  Sxy += b3v.z; Sss += b3v.w;
      Sxy += b4v.x; Sss += b4v.y;  Sxy += b4v.z; Sss += b4v.w;
      Sxy += b5v.x; Sss += b5v.y;  Sxy += b5v.z; Sss += b5v.w;
      const float Sxy1 = Sxy - b0v.z + b6v.x;
      const float Sss1 = Sss - b0v.w + b6v.y;

      acc += ssim1(Sx,  Sy,  Sxy,  Sss);
      acc += ssim1(Sx1, Sy1, Sxy1, Sss1);
    }
    curO = oN;
  };

  // 26 input rows: warmup 10 (slide-only), then 16 emitting bodies.
  // Moderate unroll with REAL back-edges (R11: straight-line bodies ->
  // giant live ranges -> 256 VGPR + 300MB scratch; never again).
  #pragma clang loop unroll_count(2)
  for (int it = 0; it < 10; ++it) body(it, false);
  #pragma clang loop unroll_count(2)
  for (int it = 10; it < 26; ++it) body(it, true);

  // per-wave reduction -> per-unit partial slot (written unconditionally: no
  // memset of d_ws needed, no atomics; waves are fully independent)
  #pragma unroll
  for (int off = 32; off > 0; off >>= 1) acc += __shfl_down(acc, off, 64);
  if (l == 0) ws[unit] = acc;
}

__global__ void ssim_final(const float* __restrict__ ws, float* __restrict__ out) {
  const int b = blockIdx.x;              // batch element
  const int t = threadIdx.x;             // 64 threads
  const float* p = ws + b * BLKS_PER_B;  // 384 partials per batch elem
  float s = 0.f;
  #pragma unroll
  for (int k = 0; k < BLKS_PER_B/64; ++k) s += p[t + 64*k];
  #pragma unroll
  for (int off = 32; off > 0; off >>= 1) s += __shfl_down(s, off, 64);
  if (t == 0) out[b] = 1.0f - s * (1.0f / (float)(NCH*HH*WW));
}

extern "C" void kernel_launch(void* const* d_in, const int* in_sizes, int n_in,
                              void* d_out, int out_size, void* d_ws, size_t ws_size,
                              hipStream_t stream) {
  const float* pred = (const float*)d_in[0];
  const float* targ = (const float*)d_in[1];
  float* out = (float*)d_out;
  float* ws  = (float*)d_ws;
  ssim_main<<<dim3(NUNITS/NWAVE), dim3(NT), 0, stream>>>(pred, targ, ws);
  ssim_final<<<dim3(NBATCH), dim3(64), 0, stream>>>(ws, out);
}

// Round 11
// 141.604 us; speedup vs baseline: 1.0699x; 1.0412x over previous
//
#include <hip/hip_runtime.h>

#define HH 512
#define WW 512
#define NCH 3
#define NBATCH 16
#define NIMG (NBATCH*NCH)     // 48
#define CHUNK 16              // output rows per wave
#define NCHUNK (HH/CHUNK)     // 32
#define NSTRIP 4              // 128-col strips
#define SW 128
#define SLOTS 142             // pad=6: col c <-> slot c-c0+6, slots 0..141
#define NWAVE 4               // waves per block (independent units, no barriers)
#define NT (64*NWAVE)         // 256 threads
#define NUNITS (NIMG*NCHUNK*NSTRIP)      // 6144 wave-units
#define BLKS_PER_B (NCH*NCHUNK*NSTRIP)   // 384 partial slots per batch elem

struct RowData { float4 m; float2 h; };

// R18 = R17 + BRANCHLESS CONSTANT-COUNT LOADS.
//  Diagnosis: R15-R17 pinned at ~58-65us with ALL pipes <=45% busy and ~90%
//  of wave time stalled — insensitive to occupancy, prefetch shape, LDS
//  conflicts. Shared constant: loads sat inside wave-uniform/divergent
//  branches (if r<HH / if hval), so outstanding-VMEM count is dynamic and the
//  compiler must drain with s_waitcnt vmcnt(0) before each use — every body
//  waits for its OWN just-issued prefetch (row it+3), exposing full latency
//  per body. Fix: clamp addresses (min/max), ALWAYS issue the same loads,
//  multiply by 0/1 validity mask (numerically identical — OOB contributed
//  exactly 0.0 before). Warm/steady loop split removes the loadold branch:
//  warm bodies never load old (pre-window empty, R14 lesson), steady bodies
//  always do. Constant VMEM stream -> counted vmcnt -> prefetch stays in
//  flight across bodies.
//  Carried: R17 4-wave packing (no barriers, per-wave LDS slices), R15/R16
//  ring-free vertical slide + slide-only warmup.
__global__ __launch_bounds__(NT) void ssim_main(
    const float* __restrict__ pred, const float* __restrict__ targ,
    float* __restrict__ ws)
{
  // per-wave vertical-sum staging slices (same-wave in-order LDS; no barriers
  // — validated R2-R17). Row stride 142*8B = 16B multiple -> rows 16B-aligned.
  __shared__ __align__(16) float2 arrA[NWAVE][SLOTS];   // (Sx, Sy) per col
  __shared__ __align__(16) float2 arrB[NWAVE][SLOTS];   // (Sxy, Sss) per col

  const int tid = threadIdx.x;
  const int wid = tid >> 6;              // wave id 0..3
  const int l   = tid & 63;              // lane id
  const int unit = blockIdx.x * NWAVE + wid;   // == old single-wave blk id
  const int img = unit >> 7;             // / (NCHUNK*NSTRIP) = /128
  const int rem = unit & 127;
  const int chunk = rem >> 2;
  const int strip = rem & 3;

  const int r0 = chunk*CHUNK - 5;        // first input row
  const int c0 = strip*SW;

  const size_t ib = (size_t)img * (size_t)(HH*WW);
  const float* pp = pred + ib;
  const float* tp = targ + ib;

  const int cm = c0 + 2*l;               // this lane's 2 main cols
  const int h  = l - 54;                 // halo id 0..9 on lanes 54..63
  const int ch = (h < 5) ? (c0 - 5 + h) : (c0 + 123 + h);   // halo col
  const bool hval = (l >= 54) && ((unsigned)ch < (unsigned)WW);
  const int chc = min(max(ch, 0), WW-1); // clamped halo col (always loadable)
  const int hs = (h < 5) ? (1 + h) : (129 + h);  // halo slot (pad=6)

  float2* const wA = arrA[wid];
  float2* const wB = arrB[wid];

  // BRANCHLESS row load: constant instruction stream (2x b64 + 2x b32 every
  // call), clamped addresses, 0/1 mask preserves zero-padding semantics.
  auto loadrow_nb = [&](int it) -> RowData {
    const int r = r0 + it;
    const int rc = min(max(r, 0), HH-1);
    const float mask = ((unsigned)r < (unsigned)HH) ? 1.f : 0.f;
    const float hm = hval ? mask : 0.f;
    const size_t ro = (size_t)rc * WW;
    const float2 x = *(const float2*)(pp + ro + cm);
    const float2 y = *(const float2*)(tp + ro + cm);
    const float hx = pp[ro + chc], hy = tp[ro + chc];
    RowData d;
    d.m = make_float4(x.x*mask, x.y*mask, y.x*mask, y.y*mask);
    d.h = make_float2(hx*hm, hy*hm);
    return d;
  };

  // vertical running sums over the 11-row window — all registers, no history
  float vx0=0.f, vy0=0.f, vxy0=0.f, vss0=0.f;    // main col 0 (cm)
  float vx1=0.f, vy1=0.f, vxy1=0.f, vss1=0.f;    // main col 1 (cm+1)
  float vxh=0.f, vyh=0.f, vxyh=0.f, vssh=0.f;    // halo col (lanes 54..63)
  float acc = 0.f;

  const RowData zrow = { make_float4(0.f,0.f,0.f,0.f), make_float2(0.f,0.f) };

  // prefetch: new-row stream 3-deep; old-row stream starts as zeros
  RowData curN = loadrow_nb(0);
  RowData nxtN = loadrow_nb(1);
  RowData nx2N = loadrow_nb(2);
  RowData curO = zrow;                   // pre-window -> zeros (R14 lesson)

  constexpr float c1 = 0.0001f, c2 = 0.0009f, inv121 = 1.0f/121.0f;

  auto ssim1 = [&](float Sx, float Sy, float Sxy, float Sss) -> float {
    const float mux = Sx*inv121, muy = Sy*inv121;
    const float muxy = mux*muy;
    const float m2   = fmaf(mux, mux, muy*muy);
    const float sgxy = fmaf(Sxy, inv121, -muxy);
    const float sgss = fmaf(Sss, inv121, -m2);
    const float num = fmaf(2.f, muxy, c1) * fmaf(2.f, sgxy, c2);
    const float den = (m2 + c1) * (sgss + c2);
    const float s = num * __builtin_amdgcn_rcpf(den);
    return fminf(fmaxf(s, 0.f), 1.f);
  };

  // shared slide step (pure VALU)
  auto slide = [&](const RowData& nw, const RowData& od) {
    const float xn0 = nw.m.x, xn1 = nw.m.y;
    const float yn0 = nw.m.z, yn1 = nw.m.w;
    const float xo0 = od.m.x, xo1 = od.m.y;
    const float yo0 = od.m.z, yo1 = od.m.w;
    vx0  += xn0 - xo0;  vy0  += yn0 - yo0;
    vx1  += xn1 - xo1;  vy1  += yn1 - yo1;
    vxy0 += xn0*yn0 - xo0*yo0;
    vxy1 += xn1*yn1 - xo1*yo1;
    vss0 += fmaf(xn0, xn0, yn0*yn0) - fmaf(xo0, xo0, yo0*yo0);
    vss1 += fmaf(xn1, xn1, yn1*yn1) - fmaf(xo1, xo1, yo1*yo1);
    const float xnh = nw.h.x, ynh = nw.h.y;
    const float xoh = od.h.x, yoh = od.h.y;
    vxh  += xnh - xoh;  vyh  += ynh - yoh;
    vxyh += xnh*ynh - xoh*yoh;
    vssh += fmaf(xnh, xnh, ynh*ynh) - fmaf(xoh, xoh, yoh*yoh);
  };

  // warmup bodies 0..9: slide-only; old row is structurally ZERO (no load,
  // no branch). New-row prefetch stays 3-deep and unconditional.
  #pragma clang loop unroll_count(2)
  for (int it = 0; it < 10; ++it) {
    slide(curN, zrow);
    curN = nxtN; nxtN = nx2N;
    nx2N = loadrow_nb(it + 3);
  }

  // steady bodies 10..25: old row ALWAYS loaded (it-10 in [0,15] — no
  // branch), emit always on.
  #pragma clang loop unroll_count(2)
  for (int it = 10; it < 26; ++it) {
    slide(curN, curO);

    // advance prefetch streams (old row issued a full body before use)
    curN = nxtN; nxtN = nx2N;
    nx2N = loadrow_nb(it + 3);
    RowData oN = loadrow_nb(it - 10);    // old row for body it+1

    // stage vertical sums: ONE aligned conflict-free b128 per array
    // (16B/lane stride) + halo b64 on 10 lanes
    *(float4*)(wA + 6 + 2*l) = make_float4(vx0, vy0, vx1, vy1);
    *(float4*)(wB + 6 + 2*l) = make_float4(vxy0, vss0, vxy1, vss1);
    if (l >= 54) {
      wA[hs] = make_float2(vxh, vyh);
      wB[hs] = make_float2(vxyh, vssh);
    }

    // horizontal 11-tap window, pure adds. Element j of the b128 read at
    // (float4*)wA + l + j covers slots {2l+2j, 2l+2j+1}; col0 window =
    // slots 2l+1..2l+11, col1 = col0 - slot(2l+1) + slot(2l+12)
    const float4* ta = (const float4*)(wA) + l;
    const float4 a0v = ta[0], a1v = ta[1], a2v = ta[2], a3v = ta[3],
                 a4v = ta[4], a5v = ta[5], a6v = ta[6];
    const float4* tb = (const float4*)(wB) + l;
    const float4 b0v = tb[0], b1v = tb[1], b2v = tb[2], b3v = tb[3],
                 b4v = tb[4], b5v = tb[5], b6v = tb[6];

    float Sx = a0v.z, Sy = a0v.w;
    Sx += a1v.x; Sy += a1v.y;  Sx += a1v.z; Sy += a1v.w;
    Sx += a2v.x; Sy += a2v.y;  Sx += a2v.z; Sy += a2v.w;
    Sx += a3v.x; Sy += a3v.y;  Sx += a3v.z; Sy += a3v.w;
    Sx += a4v.x; Sy += a4v.y;  Sx += a4v.z; Sy += a4v.w;
    Sx += a5v.x; Sy += a5v.y;  Sx += a5v.z; Sy += a5v.w;
    const float Sx1 = Sx - a0v.z + a6v.x;
    const float Sy1 = Sy - a0v.w + a6v.y;

    float Sxy = b0v.z, Sss = b0v.w;
    Sxy += b1v.x; Sss += b1v.y;  Sxy += b1v.z; Sss += b1v.w;
    Sxy += b2v.x; Sss += b2v.y;  Sxy += b2v.z; Sss += b2v.w;
    Sxy += b3v.x; Sss += b3v.y;  Sxy += b3v.z; Sss += b3v.w;
    Sxy += b4v.x; Sss += b4v.y;  Sxy += b4v.z; Sss += b4v.w;
    Sxy += b5v.x; Sss += b5v.y;  Sxy += b5v.z; Sss += b5v.w;
    const float Sxy1 = Sxy - b0v.z + b6v.x;
    const float Sss1 = Sss - b0v.w + b6v.y;

    acc += ssim1(Sx,  Sy,  Sxy,  Sss);
    acc += ssim1(Sx1, Sy1, Sxy1, Sss1);

    curO = oN;
  }

  // per-wave reduction -> per-unit partial slot (written unconditionally: no
  // memset of d_ws needed, no atomics; waves are fully independent)
  #pragma unroll
  for (int off = 32; off > 0; off >>= 1) acc += __shfl_down(acc, off, 64);
  if (l == 0) ws[unit] = acc;
}

__global__ void ssim_final(const float* __restrict__ ws, float* __restrict__ out) {
  const int b = blockIdx.x;              // batch element
  const int t = threadIdx.x;             // 64 threads
  const float* p = ws + b * BLKS_PER_B;  // 384 partials per batch elem
  float s = 0.f;
  #pragma unroll
  for (int k = 0; k < BLKS_PER_B/64; ++k) s += p[t + 64*k];
  #pragma unroll
  for (int off = 32; off > 0; off >>= 1) s += __shfl_down(s, off, 64);
  if (t == 0) out[b] = 1.0f - s * (1.0f / (float)(NCH*HH*WW));
}

extern "C" void kernel_launch(void* const* d_in, const int* in_sizes, int n_in,
                              void* d_out, int out_size, void* d_ws, size_t ws_size,
                              hipStream_t stream) {
  const float* pred = (const float*)d_in[0];
  const float* targ = (const float*)d_in[1];
  float* out = (float*)d_out;
  float* ws  = (float*)d_ws;
  ssim_main<<<dim3(NUNITS/NWAVE), dim3(NT), 0, stream>>>(pred, targ, ws);
  ssim_final<<<dim3(NBATCH), dim3(64), 0, stream>>>(ws, out);
}

// Round 13
// 141.522 us; speedup vs baseline: 1.0705x; 1.0006x over previous
//
#include <hip/hip_runtime.h>

#define HH 512
#define WW 512
#define NCH 3
#define NBATCH 16
#define NIMG (NBATCH*NCH)     // 48
#define CHUNK 16              // output rows per wave
#define NCHUNK (HH/CHUNK)     // 32
#define NSTRIP 4              // 128-col strips
#define SW 128
#define SLOTS 142             // pad=6: col c <-> slot c-c0+6, slots 0..141
#define NWAVE 4               // waves per block (independent units, no barriers)
#define NT (64*NWAVE)         // 256 threads
#define NUNITS (NIMG*NCHUNK*NSTRIP)      // 6144 wave-units
#define BLKS_PER_B (NCH*NCHUNK*NSTRIP)   // 384 partial slots per batch elem

struct RowData { float4 m; float2 h; };

// R21 = R20 (3-deep old-row pipeline) with the OFF-BY-ONE FIXED.
//  R20 bug: steady body it must subtract row it-11 (body 10 subtracts
//  NOTHING — its window is rows 0..10). R20 fed o0=row0 to body 10 and
//  refilled with loadrow(it-7): the old stream ran one row early (subtracted
//  it-10) -> absmax 0.176. Fix: initial {o0=zrow, o1=row0, o2=row1} and
//  refill loadrow_nb(it-8): loaded at body it, consumed at body it+3 as row
//  (it+3)-11 — the intended 3-body (~1000cyc) lead, correctly indexed.
//  Rationale (R18 post-mortem): the old-row load had a 1-body (~350cyc) lead
//  vs 200-900cyc L2 latency -> every steady body stalled at its first
//  instruction. R18's branchless constant-count loads (the 64->55us win)
//  keep the VMEM stream counted -> prefetch survives across bodies.
//  Carried: R17 4-wave packing (no barriers), R15/R16 ring-free vertical
//  slide + slide-only warmup.
__global__ __launch_bounds__(NT) void ssim_main(
    const float* __restrict__ pred, const float* __restrict__ targ,
    float* __restrict__ ws)
{
  // per-wave vertical-sum staging slices (same-wave in-order LDS; no barriers
  // — validated R2-R18). Row stride 142*8B = 16B multiple -> rows 16B-aligned.
  __shared__ __align__(16) float2 arrA[NWAVE][SLOTS];   // (Sx, Sy) per col
  __shared__ __align__(16) float2 arrB[NWAVE][SLOTS];   // (Sxy, Sss) per col

  const int tid = threadIdx.x;
  const int wid = tid >> 6;              // wave id 0..3
  const int l   = tid & 63;              // lane id
  const int unit = blockIdx.x * NWAVE + wid;   // == old single-wave blk id
  const int img = unit >> 7;             // / (NCHUNK*NSTRIP) = /128
  const int rem = unit & 127;
  const int chunk = rem >> 2;
  const int strip = rem & 3;

  const int r0 = chunk*CHUNK - 5;        // first input row
  const int c0 = strip*SW;

  const size_t ib = (size_t)img * (size_t)(HH*WW);
  const float* pp = pred + ib;
  const float* tp = targ + ib;

  const int cm = c0 + 2*l;               // this lane's 2 main cols
  const int h  = l - 54;                 // halo id 0..9 on lanes 54..63
  const int ch = (h < 5) ? (c0 - 5 + h) : (c0 + 123 + h);   // halo col
  const bool hval = (l >= 54) && ((unsigned)ch < (unsigned)WW);
  const int chc = min(max(ch, 0), WW-1); // clamped halo col (always loadable)
  const int hs = (h < 5) ? (1 + h) : (129 + h);  // halo slot (pad=6)

  float2* const wA = arrA[wid];
  float2* const wB = arrB[wid];

  // BRANCHLESS row load: constant instruction stream (2x b64 + 2x b32 every
  // call), clamped addresses, 0/1 mask preserves zero-padding semantics.
  auto loadrow_nb = [&](int it) -> RowData {
    const int r = r0 + it;
    const int rc = min(max(r, 0), HH-1);
    const float mask = ((unsigned)r < (unsigned)HH) ? 1.f : 0.f;
    const float hm = hval ? mask : 0.f;
    const size_t ro = (size_t)rc * WW;
    const float2 x = *(const float2*)(pp + ro + cm);
    const float2 y = *(const float2*)(tp + ro + cm);
    const float hx = pp[ro + chc], hy = tp[ro + chc];
    RowData d;
    d.m = make_float4(x.x*mask, x.y*mask, y.x*mask, y.y*mask);
    d.h = make_float2(hx*hm, hy*hm);
    return d;
  };

  // vertical running sums over the 11-row window — all registers, no history
  float vx0=0.f, vy0=0.f, vxy0=0.f, vss0=0.f;    // main col 0 (cm)
  float vx1=0.f, vy1=0.f, vxy1=0.f, vss1=0.f;    // main col 1 (cm+1)
  float vxh=0.f, vyh=0.f, vxyh=0.f, vssh=0.f;    // halo col (lanes 54..63)
  float acc = 0.f;

  const RowData zrow = { make_float4(0.f,0.f,0.f,0.f), make_float2(0.f,0.f) };

  // prefetch: new-row stream 3-deep; old-row stream starts during warmup
  RowData curN = loadrow_nb(0);
  RowData nxtN = loadrow_nb(1);
  RowData nx2N = loadrow_nb(2);

  constexpr float c1 = 0.0001f, c2 = 0.0009f, inv121 = 1.0f/121.0f;

  auto ssim1 = [&](float Sx, float Sy, float Sxy, float Sss) -> float {
    const float mux = Sx*inv121, muy = Sy*inv121;
    const float muxy = mux*muy;
    const float m2   = fmaf(mux, mux, muy*muy);
    const float sgxy = fmaf(Sxy, inv121, -muxy);
    const float sgss = fmaf(Sss, inv121, -m2);
    const float num = fmaf(2.f, muxy, c1) * fmaf(2.f, sgxy, c2);
    const float den = (m2 + c1) * (sgss + c2);
    const float s = num * __builtin_amdgcn_rcpf(den);
    return fminf(fmaxf(s, 0.f), 1.f);
  };

  // shared slide step (pure VALU)
  auto slide = [&](const RowData& nw, const RowData& od) {
    const float xn0 = nw.m.x, xn1 = nw.m.y;
    const float yn0 = nw.m.z, yn1 = nw.m.w;
    const float xo0 = od.m.x, xo1 = od.m.y;
    const float yo0 = od.m.z, yo1 = od.m.w;
    vx0  += xn0 - xo0;  vy0  += yn0 - yo0;
    vx1  += xn1 - xo1;  vy1  += yn1 - yo1;
    vxy0 += xn0*yn0 - xo0*yo0;
    vxy1 += xn1*yn1 - xo1*yo1;
    vss0 += fmaf(xn0, xn0, yn0*yn0) - fmaf(xo0, xo0, yo0*yo0);
    vss1 += fmaf(xn1, xn1, yn1*yn1) - fmaf(xo1, xo1, yo1*yo1);
    const float xnh = nw.h.x, ynh = nw.h.y;
    const float xoh = od.h.x, yoh = od.h.y;
    vxh  += xnh - xoh;  vyh  += ynh - yoh;
    vxyh += xnh*ynh - xoh*yoh;
    vssh += fmaf(xnh, xnh, ynh*ynh) - fmaf(xoh, xoh, yoh*yoh);
  };

  auto advN = [&](int it) {
    curN = nxtN; nxtN = nx2N;
    nx2N = loadrow_nb(it + 3);
  };

  // warmup bodies 0..7: slide-only; old row structurally ZERO (no load)
  #pragma clang loop unroll_count(2)
  for (int it = 0; it < 8; ++it) {
    slide(curN, zrow);
    advN(it);
  }
  // warmup bodies 8..9: also start the old stream. Body 11 subtracts row 0,
  // body 12 row 1; body 10 subtracts NOTHING (o0 = zrow — R20's bug was
  // feeding row 0 to body 10).
  slide(curN, zrow); advN(8);
  RowData o1 = loadrow_nb(0);
  slide(curN, zrow); advN(9);
  RowData o2 = loadrow_nb(1);
  RowData o0 = zrow;

  // steady bodies 10..25: body it subtracts row it-11 from the 3-deep old
  // pipeline; refill loadrow_nb(it-8) is consumed at body it+3. Emit always.
  #pragma clang loop unroll_count(2)
  for (int it = 10; it < 26; ++it) {
    slide(curN, o0);

    // advance prefetch streams (old stream keeps a 3-body lead)
    advN(it);
    o0 = o1; o1 = o2;
    o2 = loadrow_nb(it - 8);

    // stage vertical sums: ONE aligned conflict-free b128 per array
    // (16B/lane stride) + halo b64 on 10 lanes
    *(float4*)(wA + 6 + 2*l) = make_float4(vx0, vy0, vx1, vy1);
    *(float4*)(wB + 6 + 2*l) = make_float4(vxy0, vss0, vxy1, vss1);
    if (l >= 54) {
      wA[hs] = make_float2(vxh, vyh);
      wB[hs] = make_float2(vxyh, vssh);
    }

    // horizontal 11-tap window, pure adds. Element j of the b128 read at
    // (float4*)wA + l + j covers slots {2l+2j, 2l+2j+1}; col0 window =
    // slots 2l+1..2l+11, col1 = col0 - slot(2l+1) + slot(2l+12)
    const float4* ta = (const float4*)(wA) + l;
    const float4 a0v = ta[0], a1v = ta[1], a2v = ta[2], a3v = ta[3],
                 a4v = ta[4], a5v = ta[5], a6v = ta[6];
    const float4* tb = (const float4*)(wB) + l;
    const float4 b0v = tb[0], b1v = tb[1], b2v = tb[2], b3v = tb[3],
                 b4v = tb[4], b5v = tb[5], b6v = tb[6];

    float Sx = a0v.z, Sy = a0v.w;
    Sx += a1v.x; Sy += a1v.y;  Sx += a1v.z; Sy += a1v.w;
    Sx += a2v.x; Sy += a2v.y;  Sx += a2v.z; Sy += a2v.w;
    Sx += a3v.x; Sy += a3v.y;  Sx += a3v.z; Sy += a3v.w;
    Sx += a4v.x; Sy += a4v.y;  Sx += a4v.z; Sy += a4v.w;
    Sx += a5v.x; Sy += a5v.y;  Sx += a5v.z; Sy += a5v.w;
    const float Sx1 = Sx - a0v.z + a6v.x;
    const float Sy1 = Sy - a0v.w + a6v.y;

    float Sxy = b0v.z, Sss = b0v.w;
    Sxy += b1v.x; Sss += b1v.y;  Sxy += b1v.z; Sss += b1v.w;
    Sxy += b2v.x; Sss += b2v.y;  Sxy += b2v.z; Sss += b2v.w;
    Sxy += b3v.x; Sss += b3v.y;  Sxy += b3v.z; Sss += b3v.w;
    Sxy += b4v.x; Sss += b4v.y;  Sxy += b4v.z; Sss += b4v.w;
    Sxy += b5v.x; Sss += b5v.y;  Sxy += b5v.z; Sss += b5v.w;
    const float Sxy1 = Sxy - b0v.z + b6v.x;
    const float Sss1 = Sss - b0v.w + b6v.y;

    acc += ssim1(Sx,  Sy,  Sxy,  Sss);
    acc += ssim1(Sx1, Sy1, Sxy1, Sss1);
  }

  // per-wave reduction -> per-unit partial slot (written unconditionally: no
  // memset of d_ws needed, no atomics; waves are fully independent)
  #pragma unroll
  for (int off = 32; off > 0; off >>= 1) acc += __shfl_down(acc, off, 64);
  if (l == 0) ws[unit] = acc;
}

__global__ void ssim_final(const float* __restrict__ ws, float* __restrict__ out) {
  const int b = blockIdx.x;              // batch element
  const int t = threadIdx.x;             // 64 threads
  const float* p = ws + b * BLKS_PER_B;  // 384 partials per batch elem
  float s = 0.f;
  #pragma unroll
  for (int k = 0; k < BLKS_PER_B/64; ++k) s += p[t + 64*k];
  #pragma unroll
  for (int off = 32; off > 0; off >>= 1) s += __shfl_down(s, off, 64);
  if (t == 0) out[b] = 1.0f - s * (1.0f / (float)(NCH*HH*WW));
}

extern "C" void kernel_launch(void* const* d_in, const int* in_sizes, int n_in,
                              void* d_out, int out_size, void* d_ws, size_t ws_size,
                              hipStream_t stream) {
  const float* pred = (const float*)d_in[0];
  const float* targ = (const float*)d_in[1];
  float* out = (float*)d_out;
  float* ws  = (float*)d_ws;
  ssim_main<<<dim3(NUNITS/NWAVE), dim3(NT), 0, stream>>>(pred, targ, ws);
  ssim_final<<<dim3(NBATCH), dim3(64), 0, stream>>>(ws, out);
}